// Round 9
// baseline (1205.194 us; speedup 1.0000x reference)
//
#include <hip/hip_runtime.h>
#include <math.h>

// FilterShortRange: stable partition of P pairs by ||Rij|| <= 1.6, plus
// passthrough copies and n_valid.
//
// Output layout (float32, element offsets, P = n_pairs):
//   [0,     3P)  Rij_sr   (compacted, tail zeroed)
//   [3P,    4P)  idx_i_sr (compacted, tail -1)
//   [4P,    5P)  idx_j_sr (compacted, tail -1)
//   [5P,    8P)  Rij      (copy)
//   [8P,    9P)  idx_i    (copy, as float)
//   [9P,   10P)  idx_j    (copy, as float)
//   [10P]        n_valid  (as float)
//
// R2: LDS-staged scatter so every global store stream is stride-1 coalesced.
// R3: native ext_vector types for nontemporal 16B stores (HIP float4 is a
//     class and __builtin_nontemporal_store rejects it).
// R4–R9: identical resubmits (GPU acquisition timeouts — never ran).

#define BLOCK 256
#define VPT 4
#define CHUNK (BLOCK * VPT)
#define SCAN_T 1024

typedef float vf4 __attribute__((ext_vector_type(4)));
typedef int vi4 __attribute__((ext_vector_type(4)));

__device__ __forceinline__ bool short_mask(float x, float y, float z) {
    // Must bit-match jnp.linalg.norm(Rij,axis=-1) <= 1.6 in f32 (verified
    // absmax==0.0 in round 1 — keep this expression byte-identical).
    float s = x * x + y * y + z * z;
    return sqrtf(s) <= 1.6f;
}

__global__ __launch_bounds__(BLOCK) void count_kernel(
    const float* __restrict__ Rij, int* __restrict__ counts, int P) {
    int b = blockIdx.x;
    int tid = threadIdx.x;
    int e0 = b * CHUNK + tid * VPT;
    int cnt = 0;
    if (e0 + VPT <= P) {
        const vf4* R4 = (const vf4*)Rij + (e0 * 3) / 4;
        vf4 a = R4[0], c = R4[1], d = R4[2];
        cnt += short_mask(a.x, a.y, a.z);
        cnt += short_mask(a.w, c.x, c.y);
        cnt += short_mask(c.z, c.w, d.x);
        cnt += short_mask(d.y, d.z, d.w);
    } else {
        for (int j = 0; j < VPT; ++j) {
            int p = e0 + j;
            if (p < P) {
                float x = Rij[3 * p], y = Rij[3 * p + 1], z = Rij[3 * p + 2];
                cnt += short_mask(x, y, z);
            }
        }
    }
    for (int off = 32; off > 0; off >>= 1) cnt += __shfl_down(cnt, off);
    __shared__ int sm[BLOCK / 64];
    int lane = tid & 63, wid = tid >> 6;
    if (lane == 0) sm[wid] = cnt;
    __syncthreads();
    if (tid == 0) {
        int t = 0;
        for (int w = 0; w < BLOCK / 64; ++w) t += sm[w];
        counts[b] = t;
    }
}

// 1 block, SCAN_T threads; each thread owns a contiguous segment of counts.
__global__ __launch_bounds__(SCAN_T) void scan_kernel(
    const int* __restrict__ counts, int* __restrict__ offsets, int nb,
    int* __restrict__ nvalid_ws, float* __restrict__ nvalid_out) {
    int tid = threadIdx.x;
    int seg = (nb + SCAN_T - 1) / SCAN_T;
    int s0 = tid * seg;
    int local = 0;
    for (int k = 0; k < seg; ++k) {
        int i = s0 + k;
        if (i < nb) local += counts[i];
    }
    int lane = tid & 63, wid = tid >> 6;
    int incl = local;
    for (int off = 1; off < 64; off <<= 1) {
        int y = __shfl_up(incl, off);
        if (lane >= off) incl += y;
    }
    __shared__ int wsum[SCAN_T / 64];
    if (lane == 63) wsum[wid] = incl;
    __syncthreads();
    int wpre = 0;
    for (int w = 0; w < wid; ++w) wpre += wsum[w];
    int run = wpre + incl - local;  // exclusive prefix for this thread's segment
    for (int k = 0; k < seg; ++k) {
        int i = s0 + k;
        if (i < nb) {
            offsets[i] = run;
            run += counts[i];
        }
    }
    if (tid == 0) {
        int tot = 0;
        for (int w = 0; w < SCAN_T / 64; ++w) tot += wsum[w];
        nvalid_ws[0] = tot;
        nvalid_out[0] = (float)tot;
    }
}

__global__ __launch_bounds__(BLOCK) void scatter_kernel(
    const float* __restrict__ Rij, const int* __restrict__ idx_i,
    const int* __restrict__ idx_j, const int* __restrict__ offsets,
    const int* __restrict__ nvalid_ws, float* __restrict__ out, int P) {
    __shared__ float rs[3 * CHUNK];      // 12 KiB compacted Rij triplets
    __shared__ int iis[CHUNK];           // 4 KiB
    __shared__ int jjs[CHUNK];           // 4 KiB
    __shared__ int wsums[BLOCK / 64];

    int b = blockIdx.x;
    int tid = threadIdx.x;
    int lane = tid & 63, wid = tid >> 6;
    int e0 = b * CHUNK + tid * VPT;

    float x[VPT], y[VPT], z[VPT];
    int ii[VPT], jj[VPT];
    bool m[VPT];

    if (e0 + VPT <= P) {
        const vf4* R4 = (const vf4*)Rij + (e0 * 3) / 4;
        vf4 a = R4[0], c = R4[1], d = R4[2];
        x[0] = a.x; y[0] = a.y; z[0] = a.z;
        x[1] = a.w; y[1] = c.x; z[1] = c.y;
        x[2] = c.z; y[2] = c.w; z[2] = d.x;
        x[3] = d.y; y[3] = d.z; z[3] = d.w;
        vi4 vi = *((const vi4*)idx_i + e0 / 4);
        vi4 vj = *((const vi4*)idx_j + e0 / 4);
        ii[0] = vi.x; ii[1] = vi.y; ii[2] = vi.z; ii[3] = vi.w;
        jj[0] = vj.x; jj[1] = vj.y; jj[2] = vj.z; jj[3] = vj.w;
        for (int j = 0; j < VPT; ++j) m[j] = short_mask(x[j], y[j], z[j]);
        // long-range passthrough, vectorized nontemporal
        vf4* lrR = (vf4*)(out + 5LL * P) + (e0 * 3) / 4;
        __builtin_nontemporal_store(a, lrR + 0);
        __builtin_nontemporal_store(c, lrR + 1);
        __builtin_nontemporal_store(d, lrR + 2);
        vf4 fi = {(float)ii[0], (float)ii[1], (float)ii[2], (float)ii[3]};
        vf4 fj = {(float)jj[0], (float)jj[1], (float)jj[2], (float)jj[3]};
        __builtin_nontemporal_store(fi, (vf4*)(out + 8LL * P) + e0 / 4);
        __builtin_nontemporal_store(fj, (vf4*)(out + 9LL * P) + e0 / 4);
    } else {
        for (int j = 0; j < VPT; ++j) {
            int p = e0 + j;
            if (p < P) {
                x[j] = Rij[3 * p]; y[j] = Rij[3 * p + 1]; z[j] = Rij[3 * p + 2];
                ii[j] = idx_i[p]; jj[j] = idx_j[p];
                m[j] = short_mask(x[j], y[j], z[j]);
                out[5LL * P + 3 * p] = x[j];
                out[5LL * P + 3 * p + 1] = y[j];
                out[5LL * P + 3 * p + 2] = z[j];
                out[8LL * P + p] = (float)ii[j];
                out[9LL * P + p] = (float)jj[j];
            } else {
                m[j] = false;
            }
        }
    }

    int cnt = (int)m[0] + (int)m[1] + (int)m[2] + (int)m[3];

    // wave-inclusive scan of per-thread counts
    int xs = cnt;
    for (int off = 1; off < 64; off <<= 1) {
        int yv = __shfl_up(xs, off);
        if (lane >= off) xs += yv;
    }
    int waveExcl = xs - cnt;
    if (lane == 63) wsums[wid] = xs;
    __syncthreads();  // (A) wsums ready
    int wpre = 0;
    for (int w = 0; w < wid; ++w) wpre += wsums[w];
    int cntB = 0;
    for (int w = 0; w < BLOCK / 64; ++w) cntB += wsums[w];

    // stage compacted elements at their block-local rank
    int lv = wpre + waveExcl;
    for (int j = 0; j < VPT; ++j) {
        if (m[j]) {
            rs[3 * lv] = x[j];
            rs[3 * lv + 1] = y[j];
            rs[3 * lv + 2] = z[j];
            iis[lv] = ii[j];
            jjs[lv] = jj[j];
            ++lv;
        }
    }
    __syncthreads();  // (B) staging complete

    int gbase = offsets[b];
    int nvalid = nvalid_ws[0];
    int blockStart = b * CHUNK;
    int blockN = min(CHUNK, P - blockStart);
    int invB = blockN - cntB;
    long long tailStart = (long long)nvalid + (blockStart - gbase);

    // valid runs — contiguous, stride-1 coalesced
    for (int k = tid; k < 3 * cntB; k += BLOCK)
        __builtin_nontemporal_store(rs[k], out + 3LL * gbase + k);
    for (int k = tid; k < cntB; k += BLOCK) {
        __builtin_nontemporal_store((float)iis[k], out + 3LL * P + gbase + k);
        __builtin_nontemporal_store((float)jjs[k], out + 4LL * P + gbase + k);
    }
    // tail runs — contiguous constants
    for (int k = tid; k < 3 * invB; k += BLOCK)
        __builtin_nontemporal_store(0.0f, out + 3LL * tailStart + k);
    for (int k = tid; k < invB; k += BLOCK) {
        __builtin_nontemporal_store(-1.0f, out + 3LL * P + tailStart + k);
        __builtin_nontemporal_store(-1.0f, out + 4LL * P + tailStart + k);
    }
}

extern "C" void kernel_launch(void* const* d_in, const int* in_sizes, int n_in,
                              void* d_out, int out_size, void* d_ws, size_t ws_size,
                              hipStream_t stream) {
    const float* Rij = (const float*)d_in[0];
    const int* idx_i = (const int*)d_in[1];
    const int* idx_j = (const int*)d_in[2];
    int P = in_sizes[1];
    float* out = (float*)d_out;

    int nb = (P + CHUNK - 1) / CHUNK;
    int* counts = (int*)d_ws;
    int* offsets = counts + nb;
    int* nvalid_ws = offsets + nb;

    count_kernel<<<nb, BLOCK, 0, stream>>>(Rij, counts, P);
    scan_kernel<<<1, SCAN_T, 0, stream>>>(counts, offsets, nb, nvalid_ws,
                                          out + 10LL * P);
    scatter_kernel<<<nb, BLOCK, 0, stream>>>(Rij, idx_i, idx_j, offsets,
                                             nvalid_ws, out, P);
}